// Round 13
// baseline (239.649 us; speedup 1.0000x reference)
//
#include <hip/hip_runtime.h>
#include <hip/hip_bf16.h>
#include <math.h>

// Problem constants
#define SEQ   2048
#define HID   1024
#define NH    16
#define NKV   4
#define DH    64
#define GQ    (NH / NKV)
#define NQKV  1536          // fused QKV output width
#define KT    64            // attention key-tile
#define QB    32            // queries per block (2 q-frags per wave)
#define CH    512           // split-K chunk of keys (4 chunks)
#define NCH   (SEQ / CH)    // 4
#define PSTR  72            // Pst row stride (u16)
#define LNSC  0.2878231366f // ln(10000)/32

typedef __attribute__((ext_vector_type(8))) short bf16x8;
typedef __attribute__((ext_vector_type(4))) float f32x4;
typedef unsigned short u16;
typedef unsigned int u32;

__device__ __forceinline__ u16 f2bf(float f) {
    union { float f; unsigned u; } x; x.f = f;
    unsigned r = x.u + 0x7fffu + ((x.u >> 16) & 1u);   // RNE
    return (u16)(r >> 16);
}
__device__ __forceinline__ u32 pk2bf(float lo, float hi) {
    return (u32)f2bf(lo) | ((u32)f2bf(hi) << 16);
}
// async global->LDS: per-lane global gather, LDS dest = wave-uniform base
// + lane*16B
__device__ __forceinline__ void load_lds16(const u16* g, u16* l) {
    __builtin_amdgcn_global_load_lds(
        (const __attribute__((address_space(1))) unsigned int*)g,
        (__attribute__((address_space(3))) unsigned int*)l, 16, 0, 0);
}

// ---------------------------------------------------------------------------
// Setup: weight transposes (z=0..3) + X fp32->bf16 convert (z=4) + zero the
// split-K completion counters (block (0,0,4)). One launch, grid (64,32,5).
// ---------------------------------------------------------------------------
__global__ __launch_bounds__(256) void setup(const float* __restrict__ X,
                                             const float* __restrict__ Wq,
                                             const float* __restrict__ Wk,
                                             const float* __restrict__ Wv,
                                             const float* __restrict__ Wo,
                                             u16* __restrict__ Xb,
                                             u16* __restrict__ Wt,
                                             u16* __restrict__ WoT,
                                             int* __restrict__ cnt) {
    const int z = blockIdx.z;
    if (z == 4) {
        if (blockIdx.x == 0 && blockIdx.y == 0)
            cnt[threadIdx.x] = 0;                 // 256 counters
        const int idx = ((int)blockIdx.y * 64 + (int)blockIdx.x) * 256 + threadIdx.x;
        const float4 v = ((const float4*)X)[idx];
        ushort4 o;
        o.x = f2bf(v.x); o.y = f2bf(v.y); o.z = f2bf(v.z); o.w = f2bf(v.w);
        ((ushort4*)Xb)[idx] = o;
        return;
    }
    const float* in; u16* out; int N;
    if (z == 0)      { in = Wq; out = Wt;                             N = HID; }
    else if (z == 1) { in = Wk; out = Wt + (size_t)HID * HID;         N = 256; }
    else if (z == 2) { in = Wv; out = Wt + (size_t)(HID + 256) * HID; N = 256; }
    else             { in = Wo; out = WoT;                            N = HID; }

    const int n0 = blockIdx.x * 32;
    if (n0 >= N) return;
    const int k0 = blockIdx.y * 32;

    __shared__ float t[32][33];
    const int tx = threadIdx.x & 31;
    const int ty = threadIdx.x >> 5;
    #pragma unroll
    for (int i = 0; i < 4; ++i)
        t[ty + i * 8][tx] = in[(size_t)(k0 + ty + i * 8) * N + n0 + tx];
    __syncthreads();
    #pragma unroll
    for (int i = 0; i < 4; ++i)
        out[(size_t)(n0 + ty + i * 8) * HID + k0 + tx] = f2bf(t[tx][ty + i * 8]);
}

// ---------------------------------------------------------------------------
// QKV GEMM with fused RoPE epilogue (unchanged from R12).
// ---------------------------------------------------------------------------
__global__ __launch_bounds__(256) void gemm_qkv(const u16* __restrict__ A,
                                                const u16* __restrict__ Bt,
                                                u16* __restrict__ Qb,
                                                u16* __restrict__ Kb,
                                                u16* __restrict__ VTg) {
    __shared__ u16 Bs[2][64 * 32];

    const int tid  = threadIdx.x;
    const int lane = tid & 63;
    const int w    = tid >> 6;
    const int c    = lane & 15;
    const int quad = lane >> 4;
    const int m0   = blockIdx.y * 64;
    const int n0   = blockIdx.x * 64;

    const u16* gB  = Bt + (size_t)(n0 + w * 16 + (lane >> 2)) * HID + (lane & 3) * 8;
    u16* const bdst = (u16*)&Bs[0][0] + (w * 16) * 32;
    const u16* gA = A + (size_t)(m0 + w * 16 + c) * HID + quad * 8;

    f32x4 acc[4];
    #pragma unroll
    for (int nt = 0; nt < 4; ++nt) acc[nt] = (f32x4){0.f, 0.f, 0.f, 0.f};

    bf16x8 afc, afn;
    afc = *(const bf16x8*)gA;
    load_lds16(gB, bdst);

    for (int t = 0; t < HID / 32; ++t) {
        __syncthreads();
        if (t + 1 < HID / 32) {
            load_lds16(gB + (t + 1) * 32, bdst + ((t + 1) & 1) * (64 * 32));
            afn = *(const bf16x8*)(gA + (t + 1) * 32);
        }
        bf16x8 bfr[4];
        #pragma unroll
        for (int nt = 0; nt < 4; ++nt)
            bfr[nt] = *(const bf16x8*)&Bs[t & 1][(nt * 16 + c) * 32 + quad * 8];
        #pragma unroll
        for (int nt = 0; nt < 4; ++nt)
            acc[nt] = __builtin_amdgcn_mfma_f32_16x16x32_bf16(afc, bfr[nt], acc[nt], 0, 0, 0);
        afc = afn;
    }

    const int s0 = m0 + w * 16 + quad * 4;
    if (n0 < 1280) {
        const bool isQ = (n0 < 1024);
        #pragma unroll
        for (int nt = 0; nt < 4; ++nt) {
            const int d = nt * 16 + c;
            const float inv_freq = __expf(-(float)(d & 30) * LNSC);
            const float sgn = (d & 1) ? 1.f : -1.f;
            #pragma unroll
            for (int rg = 0; rg < 4; ++rg) {
                const float self = acc[nt][rg];
                const float partner = __shfl_xor(self, 1);
                float sn, cs;
                __sincosf((float)(s0 + rg) * inv_freq, &sn, &cs);
                float o = fmaf(partner, sgn * sn, self * cs);
                if (isQ) {
                    Qb[(size_t)(s0 + rg) * HID + n0 + d] = f2bf(o * 0.125f);
                } else {
                    const int kh = (n0 - 1024) >> 6;
                    Kb[((size_t)kh * SEQ + s0 + rg) * DH + d] = f2bf(o);
                }
            }
        }
    } else {
        const int kh = (n0 - 1280) >> 6;
        #pragma unroll
        for (int nt = 0; nt < 4; ++nt) {
            const int d = nt * 16 + c;
            ushort4 o;
            o.x = f2bf(acc[nt][0]); o.y = f2bf(acc[nt][1]);
            o.z = f2bf(acc[nt][2]); o.w = f2bf(acc[nt][3]);
            *(ushort4*)&VTg[((size_t)kh * DH + d) * SEQ + s0] = o;
        }
    }
}

// ---------------------------------------------------------------------------
// bf16 MFMA GEMM (unchanged): BM=64,BN=64,BK=32, single barrier. Wo proj.
// ---------------------------------------------------------------------------
__global__ __launch_bounds__(256) void gemm64(const u16* __restrict__ A,
                                              const u16* __restrict__ Bt,
                                              float* __restrict__ C,
                                              int K, int ldc) {
    __shared__ u16 Bs[2][64 * 32];

    const int tid  = threadIdx.x;
    const int lane = tid & 63;
    const int w    = tid >> 6;
    const int c    = lane & 15;
    const int quad = lane >> 4;
    const int m0   = blockIdx.y * 64;
    const int n0   = blockIdx.x * 64;

    const u16* gB  = Bt + (size_t)(n0 + w * 16 + (lane >> 2)) * K + (lane & 3) * 8;
    u16* const bdst = (u16*)&Bs[0][0] + (w * 16) * 32;
    const u16* gA = A + (size_t)(m0 + w * 16 + c) * K + quad * 8;

    const int T = K / 32;

    f32x4 acc[4];
    #pragma unroll
    for (int nt = 0; nt < 4; ++nt) acc[nt] = (f32x4){0.f, 0.f, 0.f, 0.f};

    bf16x8 afc, afn;
    afc = *(const bf16x8*)gA;
    load_lds16(gB, bdst);

    for (int t = 0; t < T; ++t) {
        __syncthreads();
        if (t + 1 < T) {
            load_lds16(gB + (t + 1) * 32, bdst + ((t + 1) & 1) * (64 * 32));
            afn = *(const bf16x8*)(gA + (t + 1) * 32);
        }
        bf16x8 bfr[4];
        #pragma unroll
        for (int nt = 0; nt < 4; ++nt)
            bfr[nt] = *(const bf16x8*)&Bs[t & 1][(nt * 16 + c) * 32 + quad * 8];
        #pragma unroll
        for (int nt = 0; nt < 4; ++nt)
            acc[nt] = __builtin_amdgcn_mfma_f32_16x16x32_bf16(afc, bfr[nt], acc[nt], 0, 0, 0);
        afc = afn;
    }

    #pragma unroll
    for (int nt = 0; nt < 4; ++nt)
        #pragma unroll
        for (int rg = 0; rg < 4; ++rg)
            C[(size_t)(m0 + w * 16 + quad * 4 + rg) * ldc + n0 + nt * 16 + c] = acc[nt][rg];
}

// ---------------------------------------------------------------------------
// MFMA flash attention v7 = R12 v6 + fused split-K merge (last-finisher).
// Single-chunk q-tiles write normalized At directly. Multi-chunk blocks
// write partials, release-fence, bump a per-(qt,kh) counter; the last one
// acquire-fences and merges all chunks for its 32 queries x 4 heads.
// Grid (SEQ/QB=64 reversed, NKV, NCH=4).
// ---------------------------------------------------------------------------
__global__ __launch_bounds__(256) void attn_kernel(const u16* __restrict__ Qb,
                                                   const u16* __restrict__ Kb,
                                                   const u16* __restrict__ VTg,
                                                   float* __restrict__ Opart,
                                                   float* __restrict__ lpart,
                                                   int* __restrict__ cnt,
                                                   u16* __restrict__ At) {
    __shared__ u16 Ks[2][2][64 * 32];   // [buf][d-half][key*32]
    __shared__ u16 Vs[2][2][64 * 32];   // [buf][key-half][d*32]
    __shared__ u16 Pst[4][QB * PSTR];   // per-wave [q][key]

    const int tid  = threadIdx.x;
    const int lane = tid & 63;
    const int w    = tid >> 6;
    const int c    = lane & 15;
    const int quad = lane >> 4;
    const int kh   = blockIdx.y;
    const int z    = blockIdx.z;
    const int qt   = (SEQ / QB - 1) - (int)blockIdx.x;   // heavy first
    const int q0   = qt * QB;
    const int h    = kh * GQ + w;

    const int kstart = z * CH;
    const int klim   = q0 + QB;
    if (kstart >= klim) return;                 // empty chunk
    const int kend   = (klim < kstart + CH) ? klim : (kstart + CH);
    const int ntiles = (kend - kstart + KT - 1) / KT;

    bf16x8 qf[2][2];
    #pragma unroll
    for (int g = 0; g < 2; ++g)
        #pragma unroll
        for (int ks = 0; ks < 2; ++ks)
            qf[g][ks] = *(const bf16x8*)&Qb[(size_t)(q0 + g * 16 + c) * HID + h * DH + ks * 32 + quad * 8];

    f32x4 accO[4][2];
    #pragma unroll
    for (int nt = 0; nt < 4; ++nt)
        #pragma unroll
        for (int g = 0; g < 2; ++g)
            accO[nt][g] = (f32x4){0.f, 0.f, 0.f, 0.f};
    float l[2] = {0.f, 0.f};

    const int hf = w >> 1;
    const int g0 = (w & 1) * 2;
    const int srow = (lane >> 2);
    const int scol = (lane & 3) * 8;

    {
        #pragma unroll
        for (int gi = 0; gi < 2; ++gi) {
            const int g = g0 + gi;
            load_lds16(Kb + ((size_t)kh * SEQ + kstart + g * 16 + srow) * DH + hf * 32 + scol,
                       &Ks[0][hf][(g * 16) * 32]);
            load_lds16(VTg + ((size_t)kh * DH + g * 16 + srow) * SEQ + kstart + hf * 32 + scol,
                       &Vs[0][hf][(g * 16) * 32]);
        }
    }

    for (int t = 0; t < ntiles; ++t) {
        const int kt0 = kstart + t * KT;
        __syncthreads();
        if (t + 1 < ntiles) {
            const int nk = kt0 + KT;
            const int nb = (t + 1) & 1;
            #pragma unroll
            for (int gi = 0; gi < 2; ++gi) {
                const int g = g0 + gi;
                load_lds16(Kb + ((size_t)kh * SEQ + nk + g * 16 + srow) * DH + hf * 32 + scol,
                           &Ks[nb][hf][(g * 16) * 32]);
                load_lds16(VTg + ((size_t)kh * DH + g * 16 + srow) * SEQ + nk + hf * 32 + scol,
                           &Vs[nb][hf][(g * 16) * 32]);
            }
        }
        const int b = t & 1;

        f32x4 accS[4][2];
        #pragma unroll
        for (int nS = 0; nS < 4; ++nS)
            #pragma unroll
            for (int g = 0; g < 2; ++g)
                accS[nS][g] = (f32x4){0.f, 0.f, 0.f, 0.f};
        #pragma unroll
        for (int nS = 0; nS < 4; ++nS)
            #pragma unroll
            for (int ks = 0; ks < 2; ++ks) {
                const bf16x8 kf = *(const bf16x8*)&Ks[b][ks][(nS * 16 + c) * 32 + quad * 8];
                #pragma unroll
                for (int g = 0; g < 2; ++g)
                    accS[nS][g] = __builtin_amdgcn_mfma_f32_16x16x32_bf16(kf, qf[g][ks], accS[nS][g], 0, 0, 0);
            }

        #pragma unroll
        for (int g = 0; g < 2; ++g) {
            const int q = q0 + g * 16 + c;
            #pragma unroll
            for (int nS = 0; nS < 4; ++nS) {
                const int key = kt0 + nS * 16 + quad * 4;
                const float p0 = (key + 0 <= q) ? __expf(accS[nS][g][0]) : 0.f;
                const float p1 = (key + 1 <= q) ? __expf(accS[nS][g][1]) : 0.f;
                const float p2 = (key + 2 <= q) ? __expf(accS[nS][g][2]) : 0.f;
                const float p3 = (key + 3 <= q) ? __expf(accS[nS][g][3]) : 0.f;
                l[g] += (p0 + p1) + (p2 + p3);
                u32* dst = (u32*)&Pst[w][(g * 16 + c) * PSTR + nS * 16 + quad * 4];
                dst[0] = pk2bf(p0, p1);
                dst[1] = pk2bf(p2, p3);
            }
        }
        __threadfence_block();

        #pragma unroll
        for (int ks2 = 0; ks2 < 2; ++ks2) {
            bf16x8 pf[2];
            #pragma unroll
            for (int g = 0; g < 2; ++g)
                pf[g] = *(const bf16x8*)&Pst[w][(g * 16 + c) * PSTR + ks2 * 32 + quad * 8];
            #pragma unroll
            for (int nt = 0; nt < 4; ++nt) {
                const bf16x8 vf = *(const bf16x8*)&Vs[b][ks2][(nt * 16 + c) * 32 + quad * 8];
                #pragma unroll
                for (int g = 0; g < 2; ++g)
                    accO[nt][g] = __builtin_amdgcn_mfma_f32_16x16x32_bf16(vf, pf[g], accO[nt][g], 0, 0, 0);
            }
        }
    }

    const int nchunks = (q0 + QB + CH - 1) / CH;   // contributing chunks

    if (nchunks == 1) {
        // single-chunk q-tile: normalized At directly from registers
        #pragma unroll
        for (int g = 0; g < 2; ++g) {
            float lg = l[g];
            lg += __shfl_xor(lg, 16);
            lg += __shfl_xor(lg, 32);
            const float inv = 1.0f / lg;
            u16* Ap = At + (size_t)(q0 + g * 16 + c) * HID + h * DH;
            #pragma unroll
            for (int nt = 0; nt < 4; ++nt) {
                ushort4 o;
                o.x = f2bf(accO[nt][g][0] * inv);
                o.y = f2bf(accO[nt][g][1] * inv);
                o.z = f2bf(accO[nt][g][2] * inv);
                o.w = f2bf(accO[nt][g][3] * inv);
                *(ushort4*)&Ap[nt * 16 + quad * 4] = o;
            }
        }
        return;
    }

    // multi-chunk: store partials
    #pragma unroll
    for (int g = 0; g < 2; ++g) {
        float lg = l[g];
        lg += __shfl_xor(lg, 16);
        lg += __shfl_xor(lg, 32);
        if (quad == 0)
            lpart[((size_t)z * SEQ + q0 + g * 16 + c) * NH + h] = lg;

        float* Op = Opart + ((size_t)z * SEQ + q0 + g * 16 + c) * HID + h * DH;
        #pragma unroll
        for (int nt = 0; nt < 4; ++nt)
            *(f32x4*)&Op[nt * 16 + quad * 4] = accO[nt][g];
    }

    // release: partials visible before counter bump
    __threadfence();
    __shared__ int done;
    if (tid == 0) done = atomicAdd(&cnt[qt * NKV + kh], 1);
    __syncthreads();
    if (done != nchunks - 1) return;
    __threadfence();   // acquire: see other blocks' partials

    // last finisher: merge 32 rows x 256 cols (heads kh*4..+3)
    const int col4 = tid & 63;                 // float4 col within 256
    const int hcol = kh * (GQ * DH) + col4 * 4;
    const int hh   = kh * GQ + (col4 >> 4);
    for (int r = q0 + (tid >> 6); r < q0 + QB; r += 4) {
        float4 o = {0.f, 0.f, 0.f, 0.f};
        float lsum = 0.f;
        for (int zz = 0; zz < nchunks; ++zz) {
            const float4 p = *(const float4*)&Opart[((size_t)zz * SEQ + r) * HID + hcol];
            o.x += p.x; o.y += p.y; o.z += p.z; o.w += p.w;
            lsum += lpart[((size_t)zz * SEQ + r) * NH + hh];
        }
        const float inv = 1.0f / lsum;
        ushort4 rr;
        rr.x = f2bf(o.x * inv); rr.y = f2bf(o.y * inv);
        rr.z = f2bf(o.z * inv); rr.w = f2bf(o.w * inv);
        *(ushort4*)&At[(size_t)r * HID + hcol] = rr;
    }
}

// ---------------------------------------------------------------------------
extern "C" void kernel_launch(void* const* d_in, const int* in_sizes, int n_in,
                              void* d_out, int out_size, void* d_ws, size_t ws_size,
                              hipStream_t stream) {
    const float* X  = (const float*)d_in[0];
    const float* Wq = (const float*)d_in[1];
    const float* Wk = (const float*)d_in[2];
    const float* Wv = (const float*)d_in[3];
    const float* Wo = (const float*)d_in[4];
    float* out = (float*)d_out;

    // workspace layout
    u16* Wt     = (u16*)d_ws;                        // 1536 x 1024 bf16
    u16* WoT    = Wt + (size_t)NQKV * HID;           // 1024 x 1024
    u16* Xb     = WoT + (size_t)HID * HID;           // 2048 x 1024
    u16* At     = Xb + (size_t)SEQ * HID;            // 2048 x 1024
    u16* Qb     = At + (size_t)SEQ * HID;            // 2048 x 1024
    u16* Kb     = Qb + (size_t)SEQ * HID;            // 4 x 2048 x 64
    u16* VTg    = Kb + (size_t)NKV * SEQ * DH;       // 4 x 64 x 2048
    float* Opart = (float*)(VTg + (size_t)NKV * DH * SEQ);  // NCH x 2048 x 1024 f32
    float* lpart = Opart + (size_t)NCH * SEQ * HID;  // NCH x 2048 x 16 f32
    int*   cnt   = (int*)(lpart + (size_t)NCH * SEQ * NH);  // 256 counters

    dim3 blk(256);

    setup<<<dim3(64, 32, 5), blk, 0, stream>>>(X, Wq, Wk, Wv, Wo, Xb, Wt, WoT, cnt);

    gemm_qkv<<<dim3(NQKV / 64, SEQ / 64), blk, 0, stream>>>(Xb, Wt, Qb, Kb, VTg);

    attn_kernel<<<dim3(SEQ / QB, NKV, NCH), blk, 0, stream>>>(Qb, Kb, VTg, Opart, lpart, cnt, At);

    gemm64<<<dim3(HID / 64, SEQ / 64), blk, 0, stream>>>(At, WoT, out, HID, HID);
}

// Round 14
// 135.792 us; speedup vs baseline: 1.7648x; 1.7648x over previous
//
#include <hip/hip_runtime.h>
#include <hip/hip_bf16.h>
#include <math.h>

// Problem constants
#define SEQ   2048
#define HID   1024
#define NH    16
#define NKV   4
#define DH    64
#define GQ    (NH / NKV)
#define NQKV  1536          // fused QKV output width
#define KT    64            // attention key-tile
#define QB    32            // queries per block (2 q-frags per wave)
#define CH    512           // split-K chunk of keys (4 chunks)
#define NCH   (SEQ / CH)    // 4
#define PSTR  72            // Pst row stride (u16)
#define LNSC  0.2878231366f // ln(10000)/32
#define GS    528           // gemm LDS group stride: 8 rows x 64 u16 + 16 pad
#define BUFS  (8 * GS)      // one staging buffer = 8 groups

typedef __attribute__((ext_vector_type(8))) short bf16x8;
typedef __attribute__((ext_vector_type(4))) float f32x4;
typedef unsigned short u16;
typedef unsigned int u32;

__device__ __forceinline__ u16 f2bf(float f) {
    union { float f; unsigned u; } x; x.f = f;
    unsigned r = x.u + 0x7fffu + ((x.u >> 16) & 1u);   // RNE
    return (u16)(r >> 16);
}
__device__ __forceinline__ u32 pk2bf(float lo, float hi) {
    return (u32)f2bf(lo) | ((u32)f2bf(hi) << 16);
}
// async global->LDS: per-lane global gather, LDS dest = wave-uniform base
// + lane*16B
__device__ __forceinline__ void load_lds16(const u16* g, u16* l) {
    __builtin_amdgcn_global_load_lds(
        (const __attribute__((address_space(1))) unsigned int*)g,
        (__attribute__((address_space(3))) unsigned int*)l, 16, 0, 0);
}

// ---------------------------------------------------------------------------
// Setup: weight transposes (z=0..3) + X fp32->bf16 convert (z=4), one launch.
// ---------------------------------------------------------------------------
__global__ __launch_bounds__(256) void setup(const float* __restrict__ X,
                                             const float* __restrict__ Wq,
                                             const float* __restrict__ Wk,
                                             const float* __restrict__ Wv,
                                             const float* __restrict__ Wo,
                                             u16* __restrict__ Xb,
                                             u16* __restrict__ Wt,
                                             u16* __restrict__ WoT) {
    const int z = blockIdx.z;
    if (z == 4) {
        const int idx = ((int)blockIdx.y * 64 + (int)blockIdx.x) * 256 + threadIdx.x;
        const float4 v = ((const float4*)X)[idx];
        ushort4 o;
        o.x = f2bf(v.x); o.y = f2bf(v.y); o.z = f2bf(v.z); o.w = f2bf(v.w);
        ((ushort4*)Xb)[idx] = o;
        return;
    }
    const float* in; u16* out; int N;
    if (z == 0)      { in = Wq; out = Wt;                             N = HID; }
    else if (z == 1) { in = Wk; out = Wt + (size_t)HID * HID;         N = 256; }
    else if (z == 2) { in = Wv; out = Wt + (size_t)(HID + 256) * HID; N = 256; }
    else             { in = Wo; out = WoT;                            N = HID; }

    const int n0 = blockIdx.x * 32;
    if (n0 >= N) return;
    const int k0 = blockIdx.y * 32;

    __shared__ float t[32][33];
    const int tx = threadIdx.x & 31;
    const int ty = threadIdx.x >> 5;
    #pragma unroll
    for (int i = 0; i < 4; ++i)
        t[ty + i * 8][tx] = in[(size_t)(k0 + ty + i * 8) * N + n0 + tx];
    __syncthreads();
    #pragma unroll
    for (int i = 0; i < 4; ++i)
        out[(size_t)(n0 + ty + i * 8) * HID + k0 + tx] = f2bf(t[tx][ty + i * 8]);
}

// ---------------------------------------------------------------------------
// QKV GEMM, BK=64 (8 MFMA per barrier), fused RoPE epilogue.
// BM=64,BN=64; grid (24, 32). B staged in 8-row groups (+32B pad/group),
// double-buffered; A-fragments direct from global.
// ---------------------------------------------------------------------------
__global__ __launch_bounds__(256) void gemm_qkv(const u16* __restrict__ A,
                                                const u16* __restrict__ Bt,
                                                u16* __restrict__ Qb,
                                                u16* __restrict__ Kb,
                                                u16* __restrict__ VTg) {
    __shared__ u16 Bs[2 * BUFS];

    const int tid  = threadIdx.x;
    const int lane = tid & 63;
    const int w    = tid >> 6;
    const int c    = lane & 15;
    const int quad = lane >> 4;
    const int m0   = blockIdx.y * 64;
    const int n0   = blockIdx.x * 64;

    // staging: wave w owns groups 2w, 2w+1 (rows w*16..w*16+15)
    const u16* gB0 = Bt + (size_t)(n0 + w * 16 + (lane >> 3)) * HID + (lane & 7) * 8;
    const u16* gB1 = gB0 + (size_t)8 * HID;
    const int  gofs0 = (w * 2) * GS, gofs1 = (w * 2 + 1) * GS;

    const u16* gA = A + (size_t)(m0 + w * 16 + c) * HID + quad * 8;
    const int  bfoff = (c >> 3) * GS + (c & 7) * 64 + quad * 8;

    f32x4 acc[4];
    #pragma unroll
    for (int nt = 0; nt < 4; ++nt) acc[nt] = (f32x4){0.f, 0.f, 0.f, 0.f};

    bf16x8 afc[2], afn[2];
    afc[0] = *(const bf16x8*)gA;
    afc[1] = *(const bf16x8*)(gA + 32);
    load_lds16(gB0, &Bs[gofs0]);
    load_lds16(gB1, &Bs[gofs1]);

    const int T = HID / 64;   // 16
    for (int t = 0; t < T; ++t) {
        __syncthreads();
        if (t + 1 < T) {
            const int nb = ((t + 1) & 1) * BUFS;
            load_lds16(gB0 + (t + 1) * 64, &Bs[nb + gofs0]);
            load_lds16(gB1 + (t + 1) * 64, &Bs[nb + gofs1]);
            afn[0] = *(const bf16x8*)(gA + (t + 1) * 64);
            afn[1] = *(const bf16x8*)(gA + (t + 1) * 64 + 32);
        }
        const int b = (t & 1) * BUFS;
        bf16x8 bfr[4][2];
        #pragma unroll
        for (int nt = 0; nt < 4; ++nt)
            #pragma unroll
            for (int ks = 0; ks < 2; ++ks)
                bfr[nt][ks] = *(const bf16x8*)&Bs[b + nt * (2 * GS) + ks * 32 + bfoff];
        #pragma unroll
        for (int ks = 0; ks < 2; ++ks)
            #pragma unroll
            for (int nt = 0; nt < 4; ++nt)
                acc[nt] = __builtin_amdgcn_mfma_f32_16x16x32_bf16(afc[ks], bfr[nt][ks], acc[nt], 0, 0, 0);
        afc[0] = afn[0];
        afc[1] = afn[1];
    }

    const int s0 = m0 + w * 16 + quad * 4;
    if (n0 < 1280) {
        const bool isQ = (n0 < 1024);
        #pragma unroll
        for (int nt = 0; nt < 4; ++nt) {
            const int d = nt * 16 + c;
            const float inv_freq = __expf(-(float)(d & 30) * LNSC);
            const float sgn = (d & 1) ? 1.f : -1.f;
            #pragma unroll
            for (int rg = 0; rg < 4; ++rg) {
                const float self = acc[nt][rg];
                const float partner = __shfl_xor(self, 1);
                float sn, cs;
                __sincosf((float)(s0 + rg) * inv_freq, &sn, &cs);
                float o = fmaf(partner, sgn * sn, self * cs);
                if (isQ) {
                    Qb[(size_t)(s0 + rg) * HID + n0 + d] = f2bf(o * 0.125f);
                } else {
                    const int kh = (n0 - 1024) >> 6;
                    Kb[((size_t)kh * SEQ + s0 + rg) * DH + d] = f2bf(o);
                }
            }
        }
    } else {
        const int kh = (n0 - 1280) >> 6;
        #pragma unroll
        for (int nt = 0; nt < 4; ++nt) {
            const int d = nt * 16 + c;
            ushort4 o;
            o.x = f2bf(acc[nt][0]); o.y = f2bf(acc[nt][1]);
            o.z = f2bf(acc[nt][2]); o.w = f2bf(acc[nt][3]);
            *(ushort4*)&VTg[((size_t)kh * DH + d) * SEQ + s0] = o;
        }
    }
}

// ---------------------------------------------------------------------------
// Wo GEMM, BK=64 (same structure), fp32 C output. Grid (16, 32).
// ---------------------------------------------------------------------------
__global__ __launch_bounds__(256) void gemm64(const u16* __restrict__ A,
                                              const u16* __restrict__ Bt,
                                              float* __restrict__ C,
                                              int K, int ldc) {
    __shared__ u16 Bs[2 * BUFS];

    const int tid  = threadIdx.x;
    const int lane = tid & 63;
    const int w    = tid >> 6;
    const int c    = lane & 15;
    const int quad = lane >> 4;
    const int m0   = blockIdx.y * 64;
    const int n0   = blockIdx.x * 64;

    const u16* gB0 = Bt + (size_t)(n0 + w * 16 + (lane >> 3)) * K + (lane & 7) * 8;
    const u16* gB1 = gB0 + (size_t)8 * K;
    const int  gofs0 = (w * 2) * GS, gofs1 = (w * 2 + 1) * GS;

    const u16* gA = A + (size_t)(m0 + w * 16 + c) * K + quad * 8;
    const int  bfoff = (c >> 3) * GS + (c & 7) * 64 + quad * 8;

    f32x4 acc[4];
    #pragma unroll
    for (int nt = 0; nt < 4; ++nt) acc[nt] = (f32x4){0.f, 0.f, 0.f, 0.f};

    bf16x8 afc[2], afn[2];
    afc[0] = *(const bf16x8*)gA;
    afc[1] = *(const bf16x8*)(gA + 32);
    load_lds16(gB0, &Bs[gofs0]);
    load_lds16(gB1, &Bs[gofs1]);

    const int T = K / 64;
    for (int t = 0; t < T; ++t) {
        __syncthreads();
        if (t + 1 < T) {
            const int nb = ((t + 1) & 1) * BUFS;
            load_lds16(gB0 + (t + 1) * 64, &Bs[nb + gofs0]);
            load_lds16(gB1 + (t + 1) * 64, &Bs[nb + gofs1]);
            afn[0] = *(const bf16x8*)(gA + (t + 1) * 64);
            afn[1] = *(const bf16x8*)(gA + (t + 1) * 64 + 32);
        }
        const int b = (t & 1) * BUFS;
        bf16x8 bfr[4][2];
        #pragma unroll
        for (int nt = 0; nt < 4; ++nt)
            #pragma unroll
            for (int ks = 0; ks < 2; ++ks)
                bfr[nt][ks] = *(const bf16x8*)&Bs[b + nt * (2 * GS) + ks * 32 + bfoff];
        #pragma unroll
        for (int ks = 0; ks < 2; ++ks)
            #pragma unroll
            for (int nt = 0; nt < 4; ++nt)
                acc[nt] = __builtin_amdgcn_mfma_f32_16x16x32_bf16(afc[ks], bfr[nt][ks], acc[nt], 0, 0, 0);
        afc[0] = afn[0];
        afc[1] = afn[1];
    }

    #pragma unroll
    for (int nt = 0; nt < 4; ++nt)
        #pragma unroll
        for (int rg = 0; rg < 4; ++rg)
            C[(size_t)(m0 + w * 16 + quad * 4 + rg) * ldc + n0 + nt * 16 + c] = acc[nt][rg];
}

// ---------------------------------------------------------------------------
// MFMA flash attention (R12 v6 + safe single-chunk direct-At write; NO
// fences/atomics). Grid (SEQ/QB=64 reversed, NKV, NCH=4).
// ---------------------------------------------------------------------------
__global__ __launch_bounds__(256) void attn_kernel(const u16* __restrict__ Qb,
                                                   const u16* __restrict__ Kb,
                                                   const u16* __restrict__ VTg,
                                                   float* __restrict__ Opart,
                                                   float* __restrict__ lpart,
                                                   u16* __restrict__ At) {
    __shared__ u16 Ks[2][2][64 * 32];   // [buf][d-half][key*32]
    __shared__ u16 Vs[2][2][64 * 32];   // [buf][key-half][d*32]
    __shared__ u16 Pst[4][QB * PSTR];   // per-wave [q][key]

    const int tid  = threadIdx.x;
    const int lane = tid & 63;
    const int w    = tid >> 6;
    const int c    = lane & 15;
    const int quad = lane >> 4;
    const int kh   = blockIdx.y;
    const int z    = blockIdx.z;
    const int qt   = (SEQ / QB - 1) - (int)blockIdx.x;   // heavy first
    const int q0   = qt * QB;
    const int h    = kh * GQ + w;

    const int kstart = z * CH;
    const int klim   = q0 + QB;
    if (kstart >= klim) return;                 // empty chunk
    const int kend   = (klim < kstart + CH) ? klim : (kstart + CH);
    const int ntiles = (kend - kstart + KT - 1) / KT;

    bf16x8 qf[2][2];
    #pragma unroll
    for (int g = 0; g < 2; ++g)
        #pragma unroll
        for (int ks = 0; ks < 2; ++ks)
            qf[g][ks] = *(const bf16x8*)&Qb[(size_t)(q0 + g * 16 + c) * HID + h * DH + ks * 32 + quad * 8];

    f32x4 accO[4][2];
    #pragma unroll
    for (int nt = 0; nt < 4; ++nt)
        #pragma unroll
        for (int g = 0; g < 2; ++g)
            accO[nt][g] = (f32x4){0.f, 0.f, 0.f, 0.f};
    float l[2] = {0.f, 0.f};

    const int hf = w >> 1;
    const int g0 = (w & 1) * 2;
    const int srow = (lane >> 2);
    const int scol = (lane & 3) * 8;

    {
        #pragma unroll
        for (int gi = 0; gi < 2; ++gi) {
            const int g = g0 + gi;
            load_lds16(Kb + ((size_t)kh * SEQ + kstart + g * 16 + srow) * DH + hf * 32 + scol,
                       &Ks[0][hf][(g * 16) * 32]);
            load_lds16(VTg + ((size_t)kh * DH + g * 16 + srow) * SEQ + kstart + hf * 32 + scol,
                       &Vs[0][hf][(g * 16) * 32]);
        }
    }

    for (int t = 0; t < ntiles; ++t) {
        const int kt0 = kstart + t * KT;
        __syncthreads();
        if (t + 1 < ntiles) {
            const int nk = kt0 + KT;
            const int nb = (t + 1) & 1;
            #pragma unroll
            for (int gi = 0; gi < 2; ++gi) {
                const int g = g0 + gi;
                load_lds16(Kb + ((size_t)kh * SEQ + nk + g * 16 + srow) * DH + hf * 32 + scol,
                           &Ks[nb][hf][(g * 16) * 32]);
                load_lds16(VTg + ((size_t)kh * DH + g * 16 + srow) * SEQ + nk + hf * 32 + scol,
                           &Vs[nb][hf][(g * 16) * 32]);
            }
        }
        const int b = t & 1;

        f32x4 accS[4][2];
        #pragma unroll
        for (int nS = 0; nS < 4; ++nS)
            #pragma unroll
            for (int g = 0; g < 2; ++g)
                accS[nS][g] = (f32x4){0.f, 0.f, 0.f, 0.f};
        #pragma unroll
        for (int nS = 0; nS < 4; ++nS)
            #pragma unroll
            for (int ks = 0; ks < 2; ++ks) {
                const bf16x8 kf = *(const bf16x8*)&Ks[b][ks][(nS * 16 + c) * 32 + quad * 8];
                #pragma unroll
                for (int g = 0; g < 2; ++g)
                    accS[nS][g] = __builtin_amdgcn_mfma_f32_16x16x32_bf16(kf, qf[g][ks], accS[nS][g], 0, 0, 0);
            }

        #pragma unroll
        for (int g = 0; g < 2; ++g) {
            const int q = q0 + g * 16 + c;
            #pragma unroll
            for (int nS = 0; nS < 4; ++nS) {
                const int key = kt0 + nS * 16 + quad * 4;
                const float p0 = (key + 0 <= q) ? __expf(accS[nS][g][0]) : 0.f;
                const float p1 = (key + 1 <= q) ? __expf(accS[nS][g][1]) : 0.f;
                const float p2 = (key + 2 <= q) ? __expf(accS[nS][g][2]) : 0.f;
                const float p3 = (key + 3 <= q) ? __expf(accS[nS][g][3]) : 0.f;
                l[g] += (p0 + p1) + (p2 + p3);
                u32* dst = (u32*)&Pst[w][(g * 16 + c) * PSTR + nS * 16 + quad * 4];
                dst[0] = pk2bf(p0, p1);
                dst[1] = pk2bf(p2, p3);
            }
        }
        __threadfence_block();

        #pragma unroll
        for (int ks2 = 0; ks2 < 2; ++ks2) {
            bf16x8 pf[2];
            #pragma unroll
            for (int g = 0; g < 2; ++g)
                pf[g] = *(const bf16x8*)&Pst[w][(g * 16 + c) * PSTR + ks2 * 32 + quad * 8];
            #pragma unroll
            for (int nt = 0; nt < 4; ++nt) {
                const bf16x8 vf = *(const bf16x8*)&Vs[b][ks2][(nt * 16 + c) * 32 + quad * 8];
                #pragma unroll
                for (int g = 0; g < 2; ++g)
                    accO[nt][g] = __builtin_amdgcn_mfma_f32_16x16x32_bf16(vf, pf[g], accO[nt][g], 0, 0, 0);
            }
        }
    }

    const int nchunks = (q0 + QB + CH - 1) / CH;

    if (nchunks == 1) {
        // single-chunk q-tile: write normalized At directly (own data only)
        #pragma unroll
        for (int g = 0; g < 2; ++g) {
            float lg = l[g];
            lg += __shfl_xor(lg, 16);
            lg += __shfl_xor(lg, 32);
            const float inv = 1.0f / lg;
            u16* Ap = At + (size_t)(q0 + g * 16 + c) * HID + h * DH;
            #pragma unroll
            for (int nt = 0; nt < 4; ++nt) {
                ushort4 o;
                o.x = f2bf(accO[nt][g][0] * inv);
                o.y = f2bf(accO[nt][g][1] * inv);
                o.z = f2bf(accO[nt][g][2] * inv);
                o.w = f2bf(accO[nt][g][3] * inv);
                *(ushort4*)&Ap[nt * 16 + quad * 4] = o;
            }
        }
        return;
    }

    #pragma unroll
    for (int g = 0; g < 2; ++g) {
        float lg = l[g];
        lg += __shfl_xor(lg, 16);
        lg += __shfl_xor(lg, 32);
        if (quad == 0)
            lpart[((size_t)z * SEQ + q0 + g * 16 + c) * NH + h] = lg;

        float* Op = Opart + ((size_t)z * SEQ + q0 + g * 16 + c) * HID + h * DH;
        #pragma unroll
        for (int nt = 0; nt < 4; ++nt)
            *(f32x4*)&Op[nt * 16 + quad * 4] = accO[nt][g];
    }
}

// ---------------------------------------------------------------------------
// Merge split-K partials for rows >= CH only (rows < CH were written
// directly by attn). Grid: (SEQ-CH)*HID/4/256 = 1536 blocks.
// ---------------------------------------------------------------------------
__global__ __launch_bounds__(256) void attn_reduce(const float* __restrict__ Opart,
                                                   const float* __restrict__ lpart,
                                                   u16* __restrict__ At) {
    const int idx = blockIdx.x * 256 + threadIdx.x + (CH * HID / 4);
    const int q  = idx >> 8;
    const int h  = (idx & 255) >> 4;
    const int klim = (q & ~(QB - 1)) + QB;
    float4 o = ((const float4*)Opart)[idx];
    float  l = lpart[q * NH + h];
    #pragma unroll
    for (int z = 1; z < NCH; ++z) {
        if (z * CH < klim) {
            const float4 o1 = ((const float4*)Opart)[idx + z * (SEQ * HID / 4)];
            o.x += o1.x; o.y += o1.y; o.z += o1.z; o.w += o1.w;
            l += lpart[(z * SEQ + q) * NH + h];
        }
    }
    const float inv = 1.0f / l;
    ushort4 r;
    r.x = f2bf(o.x * inv); r.y = f2bf(o.y * inv);
    r.z = f2bf(o.z * inv); r.w = f2bf(o.w * inv);
    ((ushort4*)At)[idx] = r;
}

// ---------------------------------------------------------------------------
extern "C" void kernel_launch(void* const* d_in, const int* in_sizes, int n_in,
                              void* d_out, int out_size, void* d_ws, size_t ws_size,
                              hipStream_t stream) {
    const float* X  = (const float*)d_in[0];
    const float* Wq = (const float*)d_in[1];
    const float* Wk = (const float*)d_in[2];
    const float* Wv = (const float*)d_in[3];
    const float* Wo = (const float*)d_in[4];
    float* out = (float*)d_out;

    // workspace layout
    u16* Wt     = (u16*)d_ws;                        // 1536 x 1024 bf16
    u16* WoT    = Wt + (size_t)NQKV * HID;           // 1024 x 1024
    u16* Xb     = WoT + (size_t)HID * HID;           // 2048 x 1024
    u16* At     = Xb + (size_t)SEQ * HID;            // 2048 x 1024
    u16* Qb     = At + (size_t)SEQ * HID;            // 2048 x 1024
    u16* Kb     = Qb + (size_t)SEQ * HID;            // 4 x 2048 x 64
    u16* VTg    = Kb + (size_t)NKV * SEQ * DH;       // 4 x 64 x 2048
    float* Opart = (float*)(VTg + (size_t)NKV * DH * SEQ);  // NCH x 2048 x 1024 f32
    float* lpart = Opart + (size_t)NCH * SEQ * HID;  // NCH x 2048 x 16 f32

    dim3 blk(256);

    setup<<<dim3(64, 32, 5), blk, 0, stream>>>(X, Wq, Wk, Wv, Wo, Xb, Wt, WoT);

    gemm_qkv<<<dim3(NQKV / 64, SEQ / 64), blk, 0, stream>>>(Xb, Wt, Qb, Kb, VTg);

    attn_kernel<<<dim3(SEQ / QB, NKV, NCH), blk, 0, stream>>>(Qb, Kb, VTg, Opart, lpart, At);

    attn_reduce<<<((SEQ - CH) * HID / 4) / 256, blk, 0, stream>>>(Opart, lpart, At);

    gemm64<<<dim3(HID / 64, SEQ / 64), blk, 0, stream>>>(At, WoT, out, HID, HID);
}